// Round 1
// 721.852 us; speedup vs baseline: 1.0416x; 1.0416x over previous
//
#include <hip/hip_runtime.h>

#define BN   8
#define TMAX 256
#define UMAX 128
#define U1   129   // U_MAX + 1
#define VV   512
#define SD   392   // diagonals allocated; max s read = 391
#define DMAX 384   // fixed DP trip count (max dend = 383)
#define NEG  -1e30f
#define PF   8     // prefetch ring depth (compile-time indexed -> stays in VGPRs)

__device__ __forceinline__ float logaddexpf_(float a, float b) {
    float mx = fmaxf(a, b);
    float d  = fabsf(a - b);
    return mx + __logf(1.0f + __expf(-d));
}

// One wave per (b,t,u) row of 512 logits: LSE + extract blank/emit logp.
// Lane mapping is CONTIGUOUS: r0 = elements [4L, 4L+4), r1 = [256+4L, 256+4L+4).
// Each global_load_dwordx4 covers 1 KB of fully-used 64-B lines (16 lines),
// vs the previous 32-B-strided mapping (2 KB span, 32 half-covered lines).
// Scratch layout (diagonal-major, interleaved for the DP consumer):
//   cD[b][s][L] : float4 = ( blank[s][2L], blank[s][2L+1],
//                            emitC[s][2L], emitC[s][2L+1] )
//   where emitC[s][u] = emit_logp(t, u-1) with t+(u-1)=s  (consumer-shifted)
//   xD[b][s]    : float2 = ( blank[s][128], emitC[s][128] )
__global__ __launch_bounds__(256) void lse_extract(
        const float* __restrict__ logits,
        const int*   __restrict__ y,
        const int*   __restrict__ Tl,
        const int*   __restrict__ Ul,
        float* __restrict__ cF,
        float* __restrict__ xF) {
    int lane = threadIdx.x & 63;
    int row  = blockIdx.x * 4 + (threadIdx.x >> 6);
    if (row >= BN * TMAX * U1) return;
    int b   = row / (TMAX * U1);
    int rem = row - b * (TMAX * U1);
    int t   = rem / U1;
    int u   = rem - t * U1;
    if (t >= Tl[b] || u > Ul[b]) return;     // never feeds the DP

    const float4* base = (const float4*)(logits + (size_t)row * VV);
    float4 r0 = base[lane];                  // elements [4L, 4L+4)
    float4 r1 = base[lane + 64];             // elements [256+4L, 256+4L+4)

    float m = fmaxf(fmaxf(fmaxf(r0.x, r0.y), fmaxf(r0.z, r0.w)),
                    fmaxf(fmaxf(r1.x, r1.y), fmaxf(r1.z, r1.w)));
#pragma unroll
    for (int off = 32; off > 0; off >>= 1) m = fmaxf(m, __shfl_xor(m, off));

    float s = __expf(r0.x - m) + __expf(r0.y - m) + __expf(r0.z - m) + __expf(r0.w - m)
            + __expf(r1.x - m) + __expf(r1.y - m) + __expf(r1.z - m) + __expf(r1.w - m);
#pragma unroll
    for (int off = 32; off > 0; off >>= 1) s += __shfl_xor(s, off);

    float lse = m + __logf(s);
    size_t cb = (size_t)b * SD + (t + u);
    if (lane == 0) {
        float bl = r0.x - lse;               // element 0 is lane 0's r0.x
        if (u < 128) cF[(cb * 64 + (u >> 1)) * 4 + (u & 1)] = bl;
        else         xF[cb * 2 + 0] = bl;
    }
    if (u < UMAX) {
        int yv = y[b * UMAX + u];            // wave-uniform, yv in [1, 512)
        int lsel = (yv & 255) >> 2;          // owning lane under contiguous map
        if (lane == lsel) {
            float4 rr = (yv >> 8) ? r1 : r0; // which half holds element yv
            int e = yv & 3;
            float v = (e == 0) ? rr.x : (e == 1) ? rr.y : (e == 2) ? rr.z : rr.w;
            int uc = u + 1;                  // consumer column index
            if (uc < 128) cF[(cb * 64 + (uc >> 1)) * 4 + 2 + (uc & 1)] = v - lse;
            else          xF[cb * 2 + 1] = v - lse;
        }
    }
}

// Barrier-free wavefront DP: one wave per batch (8 waves, 1 block).
// Lane L owns columns u=2L,2L+1; lane 63 also owns u=128.
// Fixed trip count DMAX; masking makes iterations past dend inert; alpha
// captured at d==dend. Ring indices are compile-time constants -> VGPRs.
// NEW: wave-uniform early break once the unroll group containing dend
// completes (loop is barrier-free, so per-wave exit is safe; ring overread
// bound unchanged: s <= 391 < SD).
__global__ __launch_bounds__(512) void dp_fused(
        const float4* __restrict__ cD,
        const float2* __restrict__ xD,
        const int*   __restrict__ Tlp,
        const int*   __restrict__ Ulp,
        float* __restrict__ out) {
    __shared__ float part[BN];
    int w = threadIdx.x >> 6;
    int L = threadIdx.x & 63;
    int Tl = Tlp[w], Ul = Ulp[w];
    int dend = Tl - 1 + Ul;
    const float4* c4 = cD + (size_t)w * SD * 64;
    const float2* x2 = xD + (size_t)w * SD;
    bool lx = (L == 63);
    int  u0 = 2 * L, u1 = 2 * L + 1;
    int  Tm1 = Tl - 1;

    float p0 = (L == 0) ? 0.0f : NEG;        // alpha on diagonal 0
    float p1 = NEG, px = NEG;
    float a0 = NEG, a1 = NEG, ax = NEG;      // captured at d == dend

    float4 ring[PF];
    float2 xr[PF];
#pragma unroll
    for (int i = 0; i < PF; ++i) {
        ring[i] = c4[i * 64 + L];
        xr[i]   = lx ? x2[i] : make_float2(NEG, NEG);
    }

    for (int dc = 1; dc <= DMAX; dc += PF) {
#pragma unroll
        for (int j = 0; j < PF; ++j) {
            int d = dc + j;                  // ring slot = j (compile-time)
            float4 f = ring[j];
            float2 g = xr[j];
            float pm1 = __shfl_up(p1, 1);
            if (L == 0) pm1 = NEG;
            // edges fall out: missing parent is NEG, LAE(NEG,x)==x
            float c0 = logaddexpf_(p0 + f.x, pm1 + f.z);
            float c1 = logaddexpf_(p1 + f.y, p0  + f.w);
            float cx = logaddexpf_(px + g.x, p1  + g.y);
            int ulo = d - Tm1; if (ulo < 0) ulo = 0;
            int uhi = (d < Ul) ? d : Ul;
            p0 = (u0 >= ulo && u0 <= uhi) ? c0 : NEG;
            p1 = (u1 >= ulo && u1 <= uhi) ? c1 : NEG;
            px = (lx && 128 >= ulo && 128 <= uhi) ? cx : NEG;
            if (d == dend) { a0 = p0; a1 = p1; ax = px; }   // wave-uniform branch
            int s = d + PF - 1;              // refill; consumed at d+PF. s<=391<SD
            ring[j] = c4[s * 64 + L];
            xr[j]   = lx ? x2[s] : make_float2(NEG, NEG);
        }
        if (dc + PF > dend) break;           // group containing dend just ran
    }

    if (Ul == 128) {
        if (lx) part[w] = ax + x2[dend].x;                  // + blank[Tl-1,128]
    } else if (L == (Ul >> 1)) {
        float af = (Ul & 1) ? a1 : a0;
        const float* cFv = (const float*)c4;
        float bl = cFv[((size_t)dend * 64 + (Ul >> 1)) * 4 + (Ul & 1)];
        part[w] = af + bl;                                  // + blank[Tl-1,Ul]
    }
    __syncthreads();
    if (threadIdx.x == 0) {
        float acc = 0.0f;
#pragma unroll
        for (int i = 0; i < BN; ++i) acc += part[i];
        *out = -acc * (1.0f / BN);
    }
}

extern "C" void kernel_launch(void* const* d_in, const int* in_sizes, int n_in,
                              void* d_out, int out_size, void* d_ws, size_t ws_size,
                              hipStream_t stream) {
    const float* logits = (const float*)d_in[0];
    const int*   y      = (const int*)d_in[1];
    const int*   Tl     = (const int*)d_in[2];
    const int*   Ul     = (const int*)d_in[3];
    float* out = (float*)d_out;

    float* cF = (float*)d_ws;                               // BN*SD*64 float4
    float* xF = cF + (size_t)BN * SD * 64 * 4;              // BN*SD float2

    int rows = BN * TMAX * U1;                              // 264192
    lse_extract<<<dim3((rows + 3) / 4), dim3(256), 0, stream>>>(
        logits, y, Tl, Ul, cF, xF);
    dp_fused<<<dim3(1), dim3(BN * 64), 0, stream>>>(
        (const float4*)cF, (const float2*)xF, Tl, Ul, out);
}